// Round 5
// baseline (239.095 us; speedup 1.0000x reference)
//
#include <hip/hip_runtime.h>
#include <hip/hip_bf16.h>
#include <hip/hip_cooperative_groups.h>

namespace cg = cooperative_groups;

#define NPTS 1024
#define HID 128
#define KNN 10
#define FLT_MAX_ 3.402823466e+38f

// ===========================================================================
// FUSED single-launch cooperative kernel.
//   grid = nP blocks (nP <= 2048), block = 256 threads.
//   Prologue (before grid sync):
//     blk 0..255   : Td[v=blk][c] = (sinusoid(v).Wd[c] + bd[c]) / 1024
//     blk 256..271 : Ta[v=blk-256][c] = sinusoid(v).Wa[c] + ba[c]
//     blk 272..272+ceil(nP/256)-1 : repack pts -> float4
//     all blocks   : zero their LDS histograms
//   grid.sync()
//   Main (per point, blk = b*1024 + i): distances+hist, pruned top-10,
//     angles->bitmask, LUT dot + masked max, store 128 channels.
// ===========================================================================
__global__ __launch_bounds__(256, 8) void gse_fused(
    const float* __restrict__ pts,
    const float* __restrict__ Wd, const float* __restrict__ bd,
    const float* __restrict__ Wa, const float* __restrict__ ba,
    float* __restrict__ Td, float* __restrict__ Ta,
    float4* __restrict__ P4, float* __restrict__ out, int nP) {
    const int blk = blockIdx.x;
    const int tid = threadIdx.x;        // 0..255
    const int lane = tid & 63;
    const int w = tid >> 6;             // wave 0..3

    __shared__ float S[HID];            // sinusoid (prologue only)
    __shared__ int h4[4][256];
    __shared__ float cd[64];
    __shared__ int cidx[64];
    __shared__ int nn[KNN];
    __shared__ float uxs[KNN], uys[KNN], uzs[KNN];
    __shared__ float sums[256], mxs[256];   // sums doubles as `part` in prologue
    __shared__ unsigned amask_s;
    __shared__ int ccnt;

    // ---- zero histograms for the main phase (overlaps prologue) ----
    {
        int* hf = (int*)h4;
        hf[tid] = 0; hf[tid + 256] = 0; hf[tid + 512] = 0; hf[tid + 768] = 0;
    }
    if (tid == 0) { amask_s = 0u; ccnt = 0; }

    // ---- prologue ----
    if (blk < 272) {
        const bool isA = (blk >= 256);
        const int v = isA ? blk - 256 : blk;
        if (tid < HID) {
            const int m = tid >> 1;
            const float dtm = expf((float)m * (float)(-9.210340371976184 / 64.0));
            const float arg = (float)v * dtm;
            S[tid] = (tid & 1) ? cosf(arg) : sinf(arg);
        }
        __syncthreads();
        const int c = tid & 127;
        const int seg = tid >> 7;            // 0..1
        const float* W = isA ? Wa : Wd;
        const float* wrow = W + c * HID + seg * 64;
        const float* srow = S + seg * 64;
        float acc = 0.0f;
        #pragma unroll
        for (int h = 0; h < 64; h += 4) {
            const float4 wv = *reinterpret_cast<const float4*>(wrow + h);
            acc += srow[h] * wv.x + srow[h + 1] * wv.y
                 + srow[h + 2] * wv.z + srow[h + 3] * wv.w;
        }
        sums[tid] = acc;
        __syncthreads();
        if (tid < HID) {
            const float s = sums[c] + sums[c + 128];
            if (isA) Ta[v * HID + c] = s + ba[c];
            else     Td[v * HID + c] = (s + bd[c]) * (1.0f / (float)NPTS);
        }
    } else if (blk < 272 + (nP + 255) / 256) {
        const int idx = (blk - 272) * 256 + tid;
        if (idx < nP) {
            P4[idx] = make_float4(pts[idx * 3 + 0], pts[idx * 3 + 1],
                                  pts[idx * 3 + 2], 0.0f);
        }
    }

    cg::this_grid().sync();

    // ================= main per-point phase =================
    const int gid = blk;
    const int b = gid >> 10;
    const int i = gid & 1023;
    const float4* P = P4 + (size_t)b * NPTS;
    const float4 p = P[i];

    // ---- phase 1: 4 distances/lane + private per-wave hist ----
    float d4[4];
    int q4[4];
    const int jb = w * 256;
    #pragma unroll
    for (int s = 0; s < 4; ++s) {
        const int j = jb + s * 64 + lane;
        const float4 q = P[j];
        const float dx = p.x - q.x;
        const float dy = p.y - q.y;
        const float dz = p.z - q.z;
        const float dd = sqrtf(dx * dx + dy * dy + dz * dz);
        d4[s] = dd;
        float qq = rintf(dd / 0.2f);    // matches jnp.round (half-to-even)
        qq = fminf(fmaxf(qq, 0.0f), 255.0f);
        q4[s] = (int)qq;
        atomicAdd(&h4[w][q4[s]], 1);
    }
    __syncthreads();

    // ---- merge hists (bin = tid) ----
    const int hsum = h4[0][tid] + h4[1][tid] + h4[2][tid] + h4[3][tid];
    h4[0][tid] = hsum;
    __syncthreads();
    const int* hist = h4[0];

    // ---- scan bins 0..63 for b10; maxbin via ballots (per-wave redundant) ----
    int cum = hist[lane];
    #pragma unroll
    for (int off = 1; off < 64; off <<= 1) {
        const int n_ = __shfl_up(cum, off);
        if (lane >= off) cum += n_;
    }
    const unsigned long long bal = __ballot(cum >= KNN);
    const unsigned long long nz0 = __ballot(hist[lane] != 0);
    const unsigned long long nz1 = __ballot(hist[64 + lane] != 0);
    const unsigned long long nz2 = __ballot(hist[128 + lane] != 0);
    const unsigned long long nz3 = __ballot(hist[192 + lane] != 0);
    int maxbin;
    if (nz3)      maxbin = 192 + 63 - __clzll((long long)nz3);
    else if (nz2) maxbin = 128 + 63 - __clzll((long long)nz2);
    else if (nz1) maxbin = 64 + 63 - __clzll((long long)nz1);
    else          maxbin = 63 - __clzll((long long)nz0);

    int b10 = 0, c = 0;
    if (bal) { b10 = __ffsll(bal) - 1; c = __shfl(cum, b10); }
    const bool fast = (bal != 0ull) && (c <= 64);   // block-uniform

    if (fast) {
        // candidates = all points with bin <= b10 (superset of top-10, c <= 64)
        #pragma unroll
        for (int s = 0; s < 4; ++s) {
            if (q4[s] <= b10) {
                const int pp = atomicAdd(&ccnt, 1);
                cd[pp] = d4[s];
                cidx[pp] = jb + s * 64 + lane;
            }
        }
        __syncthreads();
        if (tid < c) {
            const float md = cd[tid];
            const int mi = cidx[tid];
            int rank = 0;
            #pragma unroll 4
            for (int pp = 0; pp < c; ++pp) {
                const float od = cd[pp];
                const int oi = cidx[pp];
                rank += (od < md || (od == md && oi < mi)) ? 1 : 0;
            }
            if (rank < KNN) nn[rank] = mi;
        }
        __syncthreads();
    } else {
        // fallback: each wave top-10 of its 256 points, then 40-way rank merge
        unsigned valid = 0xfu;
        float keep_d = 0.0f;
        int keep_i = 0;
        for (int r = 0; r < KNN; ++r) {
            float bv = FLT_MAX_;
            int bi = 0x7fffffff;
            #pragma unroll
            for (int s = 0; s < 4; ++s) {
                if (valid & (1u << s)) {
                    const float v_ = d4[s];
                    const int id_ = jb + s * 64 + lane;
                    if (v_ < bv || (v_ == bv && id_ < bi)) { bv = v_; bi = id_; }
                }
            }
            #pragma unroll
            for (int off = 32; off > 0; off >>= 1) {
                const float ov = __shfl_xor(bv, off);
                const int oi = __shfl_xor(bi, off);
                if (ov < bv || (ov == bv && oi < bi)) { bv = ov; bi = oi; }
            }
            const int loc = bi - jb;
            if (loc >= 0 && loc < 256 && lane == (loc & 63)) valid &= ~(1u << (loc >> 6));
            if (lane == r) { keep_d = bv; keep_i = bi; }
        }
        if (lane < KNN) { cd[w * KNN + lane] = keep_d; cidx[w * KNN + lane] = keep_i; }
        __syncthreads();
        if (tid < 4 * KNN) {
            const float md = cd[tid];
            const int mi = cidx[tid];
            int rank = 0;
            for (int pp = 0; pp < 4 * KNN; ++pp) {
                const float od = cd[pp];
                const int oi = cidx[pp];
                rank += (od < md || (od == md && oi < mi)) ? 1 : 0;
            }
            if (rank < KNN) nn[rank] = mi;
        }
        __syncthreads();
    }

    // ---- phase 3: unit vectors ----
    if (tid < KNN) {
        const float4 qn = P[nn[tid]];
        const float vx = qn.x - p.x;
        const float vy = qn.y - p.y;
        const float vz = qn.z - p.z;
        const float nrm = sqrtf(vx * vx + vy * vy + vz * vz);
        const float den = nrm + 1e-8f;
        uxs[tid] = vx / den; uys[tid] = vy / den; uzs[tid] = vz / den;
    }
    __syncthreads();

    // ---- phase 4: 100 pairwise angles -> presence mask ----
    if (tid < KNN * KNN) {
        const int k = tid / KNN, l = tid % KNN;
        float cc = uxs[k] * uxs[l] + uys[k] * uys[l] + uzs[k] * uzs[l];
        cc = fminf(fmaxf(cc, -1.0f), 1.0f);
        const float ang = acosf(cc);
        float q = rintf(ang * (float)(180.0 / (15.0 * M_PI)));
        q = fminf(fmaxf(q, 0.0f), 15.0f);
        atomicOr(&amask_s, 1u << (int)q);
    }
    __syncthreads();

    // ---- phase 5: split even/odd bins + low/high mask across half-blocks ----
    const unsigned am = amask_s;
    const int c7 = tid & 127;
    const int half = tid >> 7;
    float s = 0.0f;
    const float* tdc = Td + c7;
    #pragma unroll 4
    for (int v = half; v <= maxbin; v += 2) {
        s += (float)hist[v] * tdc[v * HID];   // zero bins add exact 0.0f
    }
    float mx = -FLT_MAX_;
    const float* tac = Ta + c7;
    #pragma unroll
    for (int v = 0; v < 8; ++v) {
        const int vv = half * 8 + v;
        const float tv = tac[vv * HID];
        if (am & (1u << vv)) mx = fmaxf(mx, tv);
    }
    sums[tid] = s;
    mxs[tid] = mx;
    __syncthreads();
    if (tid < HID) {
        out[(size_t)gid * HID + tid] =
            (sums[tid] + sums[tid + 128]) + fmaxf(mxs[tid], mxs[tid + 128]);
    }
}

// ===========================================================================
// Fallback path (proven round-4 kernels), used if nP > 2048 or the
// cooperative launch is rejected.
// ===========================================================================
__global__ __launch_bounds__(512) void gse_build_tables(
    const float* __restrict__ Wd, const float* __restrict__ bd,
    const float* __restrict__ Wa, const float* __restrict__ ba,
    const float* __restrict__ pts, int nP,
    float* __restrict__ Td, float* __restrict__ Ta, float4* __restrict__ P4) {
    const int blk = blockIdx.x;
    const int tid = threadIdx.x;

    if (blk >= 272) {
        const int idx = (blk - 272) * 512 + tid;
        if (idx < nP) {
            P4[idx] = make_float4(pts[idx * 3 + 0], pts[idx * 3 + 1],
                                  pts[idx * 3 + 2], 0.0f);
        }
        return;
    }

    __shared__ float S[HID];
    __shared__ float part[512];
    const bool isA = (blk >= 256);
    const int v = isA ? blk - 256 : blk;
    const int c = tid & 127;
    const int seg = tid >> 7;

    if (tid < HID) {
        const int m = tid >> 1;
        const float dtm = expf((float)m * (float)(-9.210340371976184 / 64.0));
        const float arg = (float)v * dtm;
        S[tid] = (tid & 1) ? cosf(arg) : sinf(arg);
    }
    __syncthreads();

    const float* W = isA ? Wa : Wd;
    const float* wrow = W + c * HID + seg * 32;
    const float* srow = S + seg * 32;
    float acc = 0.0f;
    #pragma unroll
    for (int h = 0; h < 32; h += 4) {
        const float4 wv = *reinterpret_cast<const float4*>(wrow + h);
        acc += srow[h] * wv.x + srow[h + 1] * wv.y + srow[h + 2] * wv.z + srow[h + 3] * wv.w;
    }
    part[tid] = acc;
    __syncthreads();

    if (tid < HID) {
        const float s = (part[c] + part[c + 128]) + (part[c + 256] + part[c + 384]);
        if (isA) Ta[v * HID + c] = s + ba[c];
        else     Td[v * HID + c] = (s + bd[c]) * (1.0f / (float)NPTS);
    }
}

__global__ __launch_bounds__(256, 8) void gse_main(
    const float4* __restrict__ P4,
    const float* __restrict__ Td,
    const float* __restrict__ Ta,
    float* __restrict__ out) {
    const int gid = blockIdx.x;
    const int b = gid >> 10;
    const int i = gid & 1023;
    const float4* P = P4 + (size_t)b * NPTS;
    const int tid = threadIdx.x;
    const int lane = tid & 63;
    const int w = tid >> 6;

    __shared__ int h4[4][256];
    __shared__ float cd[64];
    __shared__ int cidx[64];
    __shared__ int nn[KNN];
    __shared__ float uxs[KNN], uys[KNN], uzs[KNN];
    __shared__ float sums[256], mxs[256];
    __shared__ unsigned amask_s;
    __shared__ int ccnt;

    {
        int* hf = (int*)h4;
        hf[tid] = 0; hf[tid + 256] = 0; hf[tid + 512] = 0; hf[tid + 768] = 0;
    }
    if (tid == 0) { amask_s = 0u; ccnt = 0; }
    const float4 p = P[i];
    __syncthreads();

    float d4[4];
    int q4[4];
    const int jb = w * 256;
    #pragma unroll
    for (int s = 0; s < 4; ++s) {
        const int j = jb + s * 64 + lane;
        const float4 q = P[j];
        const float dx = p.x - q.x;
        const float dy = p.y - q.y;
        const float dz = p.z - q.z;
        const float dd = sqrtf(dx * dx + dy * dy + dz * dz);
        d4[s] = dd;
        float qq = rintf(dd / 0.2f);
        qq = fminf(fmaxf(qq, 0.0f), 255.0f);
        q4[s] = (int)qq;
        atomicAdd(&h4[w][q4[s]], 1);
    }
    __syncthreads();

    const int hsum = h4[0][tid] + h4[1][tid] + h4[2][tid] + h4[3][tid];
    h4[0][tid] = hsum;
    __syncthreads();
    const int* hist = h4[0];

    int cum = hist[lane];
    #pragma unroll
    for (int off = 1; off < 64; off <<= 1) {
        const int n_ = __shfl_up(cum, off);
        if (lane >= off) cum += n_;
    }
    const unsigned long long bal = __ballot(cum >= KNN);
    const unsigned long long nz0 = __ballot(hist[lane] != 0);
    const unsigned long long nz1 = __ballot(hist[64 + lane] != 0);
    const unsigned long long nz2 = __ballot(hist[128 + lane] != 0);
    const unsigned long long nz3 = __ballot(hist[192 + lane] != 0);
    int maxbin;
    if (nz3)      maxbin = 192 + 63 - __clzll((long long)nz3);
    else if (nz2) maxbin = 128 + 63 - __clzll((long long)nz2);
    else if (nz1) maxbin = 64 + 63 - __clzll((long long)nz1);
    else          maxbin = 63 - __clzll((long long)nz0);

    int b10 = 0, c = 0;
    if (bal) { b10 = __ffsll(bal) - 1; c = __shfl(cum, b10); }
    const bool fast = (bal != 0ull) && (c <= 64);

    if (fast) {
        #pragma unroll
        for (int s = 0; s < 4; ++s) {
            if (q4[s] <= b10) {
                const int pp = atomicAdd(&ccnt, 1);
                cd[pp] = d4[s];
                cidx[pp] = jb + s * 64 + lane;
            }
        }
        __syncthreads();
        if (tid < c) {
            const float md = cd[tid];
            const int mi = cidx[tid];
            int rank = 0;
            #pragma unroll 4
            for (int pp = 0; pp < c; ++pp) {
                const float od = cd[pp];
                const int oi = cidx[pp];
                rank += (od < md || (od == md && oi < mi)) ? 1 : 0;
            }
            if (rank < KNN) nn[rank] = mi;
        }
        __syncthreads();
    } else {
        unsigned valid = 0xfu;
        float keep_d = 0.0f;
        int keep_i = 0;
        for (int r = 0; r < KNN; ++r) {
            float bv = FLT_MAX_;
            int bi = 0x7fffffff;
            #pragma unroll
            for (int s = 0; s < 4; ++s) {
                if (valid & (1u << s)) {
                    const float v_ = d4[s];
                    const int id_ = jb + s * 64 + lane;
                    if (v_ < bv || (v_ == bv && id_ < bi)) { bv = v_; bi = id_; }
                }
            }
            #pragma unroll
            for (int off = 32; off > 0; off >>= 1) {
                const float ov = __shfl_xor(bv, off);
                const int oi = __shfl_xor(bi, off);
                if (ov < bv || (ov == bv && oi < bi)) { bv = ov; bi = oi; }
            }
            const int loc = bi - jb;
            if (loc >= 0 && loc < 256 && lane == (loc & 63)) valid &= ~(1u << (loc >> 6));
            if (lane == r) { keep_d = bv; keep_i = bi; }
        }
        if (lane < KNN) { cd[w * KNN + lane] = keep_d; cidx[w * KNN + lane] = keep_i; }
        __syncthreads();
        if (tid < 4 * KNN) {
            const float md = cd[tid];
            const int mi = cidx[tid];
            int rank = 0;
            for (int pp = 0; pp < 4 * KNN; ++pp) {
                const float od = cd[pp];
                const int oi = cidx[pp];
                rank += (od < md || (od == md && oi < mi)) ? 1 : 0;
            }
            if (rank < KNN) nn[rank] = mi;
        }
        __syncthreads();
    }

    if (tid < KNN) {
        const float4 qn = P[nn[tid]];
        const float vx = qn.x - p.x;
        const float vy = qn.y - p.y;
        const float vz = qn.z - p.z;
        const float nrm = sqrtf(vx * vx + vy * vy + vz * vz);
        const float den = nrm + 1e-8f;
        uxs[tid] = vx / den; uys[tid] = vy / den; uzs[tid] = vz / den;
    }
    __syncthreads();

    if (tid < KNN * KNN) {
        const int k = tid / KNN, l = tid % KNN;
        float cc = uxs[k] * uxs[l] + uys[k] * uys[l] + uzs[k] * uzs[l];
        cc = fminf(fmaxf(cc, -1.0f), 1.0f);
        const float ang = acosf(cc);
        float q = rintf(ang * (float)(180.0 / (15.0 * M_PI)));
        q = fminf(fmaxf(q, 0.0f), 15.0f);
        atomicOr(&amask_s, 1u << (int)q);
    }
    __syncthreads();

    const unsigned am = amask_s;
    const int c7 = tid & 127;
    const int half = tid >> 7;
    float s = 0.0f;
    const float* tdc = Td + c7;
    #pragma unroll 4
    for (int v = half; v <= maxbin; v += 2) {
        s += (float)hist[v] * tdc[v * HID];
    }
    float mx = -FLT_MAX_;
    const float* tac = Ta + c7;
    #pragma unroll
    for (int v = 0; v < 8; ++v) {
        const int vv = half * 8 + v;
        const float tv = tac[vv * HID];
        if (am & (1u << vv)) mx = fmaxf(mx, tv);
    }
    sums[tid] = s;
    mxs[tid] = mx;
    __syncthreads();
    if (tid < HID) {
        out[(size_t)gid * HID + tid] =
            (sums[tid] + sums[tid + 128]) + fmaxf(mxs[tid], mxs[tid + 128]);
    }
}

extern "C" void kernel_launch(void* const* d_in, const int* in_sizes, int n_in,
                              void* d_out, int out_size, void* d_ws, size_t ws_size,
                              hipStream_t stream) {
    const float* pts = (const float*)d_in[0];
    const float* Wd  = (const float*)d_in[1];
    const float* bd  = (const float*)d_in[2];
    const float* Wa  = (const float*)d_in[3];
    const float* ba  = (const float*)d_in[4];
    float* out = (float*)d_out;

    const int B = in_sizes[0] / (NPTS * 3);
    const int nP = B * NPTS;

    float* Td = (float*)d_ws;                        // 256*128*4 = 128 KiB
    float* Ta = Td + 256 * HID;                      // 16*128*4  =   8 KiB
    float4* P4 = (float4*)(Ta + 16 * HID);           // nP*16 B

    bool done = false;
    if (nP <= 2048) {
        // single cooperative launch: grid = nP blocks, fully co-resident
        // (256 thr, <=64 VGPR via launch_bounds, ~7.5 KB LDS -> 8 blocks/CU)
        void* args[] = {(void*)&pts, (void*)&Wd, (void*)&bd, (void*)&Wa,
                        (void*)&ba, (void*)&Td, (void*)&Ta, (void*)&P4,
                        (void*)&out, (void*)&nP};
        hipError_t e = hipLaunchCooperativeKernel(
            (const void*)gse_fused, dim3(nP), dim3(256), args, 0, stream);
        done = (e == hipSuccess);
    }
    if (!done) {
        const int nconv = (nP + 511) / 512;
        gse_build_tables<<<272 + nconv, 512, 0, stream>>>(Wd, bd, Wa, ba, pts, nP, Td, Ta, P4);
        gse_main<<<nP, 256, 0, stream>>>(P4, Td, Ta, out);
    }
}

// Round 6
// 38.326 us; speedup vs baseline: 6.2384x; 6.2384x over previous
//
#include <hip/hip_runtime.h>
#include <hip/hip_bf16.h>

#define NPTS 1024
#define HID 128
#define KNN 10
#define NROWS 272
#define FLT_MAX_ 3.402823466e+38f

// ===========================================================================
// FUSED single kernel, NO grid.sync (round-5 lesson: grid.sync ~200us on 8
// XCDs). Producer/consumer instead:
//   blocks 0..255  : produce Td[v=blk]   (+ their own point, like everyone)
//   blocks 256..271: produce Ta[v=blk-256]
//   all blocks     : phases 1-4 (no table needed), then spin on flag==272
//                    (device-scope acquire) before phase 5.
// Deadlock-free: grid = nP <= 2048 = 256 CU x 8 blocks/CU full co-residency
// (proven by round-5's successful cooperative launch of this exact shape).
// flag is hipMemsetAsync'd to 0 before each launch (graph-capturable).
// ===========================================================================
__global__ __launch_bounds__(256, 8) void gse_one(
    const float* __restrict__ pts,
    const float* __restrict__ Wd, const float* __restrict__ bd,
    const float* __restrict__ Wa, const float* __restrict__ ba,
    float* __restrict__ Td, float* __restrict__ Ta,
    int* __restrict__ flag, float* __restrict__ out) {
    const int blk = blockIdx.x;
    const int tid = threadIdx.x;        // 0..255
    const int lane = tid & 63;
    const int w = tid >> 6;             // wave 0..3

    __shared__ int h4[4][256];
    __shared__ float cd[64];
    __shared__ int cidx[64];
    __shared__ int nn[KNN];
    __shared__ float sums[256], mxs[256];   // reused: part / S in producer phase
    __shared__ unsigned amask_s;
    __shared__ int ccnt;

    // ---- zero LDS hist (covered by the barrier below) ----
    {
        int* hf = (int*)h4;
        hf[tid] = 0; hf[tid + 256] = 0; hf[tid + 512] = 0; hf[tid + 768] = 0;
    }
    if (tid == 0) { amask_s = 0u; ccnt = 0; }

    // ---- producer: build one LUT row, then signal ----
    if (blk < NROWS) {
        const bool isA = (blk >= 256);
        const int v = isA ? blk - 256 : blk;
        if (tid < HID) {
            const int m = tid >> 1;
            const float dtm = expf((float)m * (float)(-9.210340371976184 / 64.0));
            const float arg = (float)v * dtm;
            mxs[tid] = (tid & 1) ? cosf(arg) : sinf(arg);    // S in mxs
        }
        __syncthreads();
        const int c = tid & 127;
        const int seg = tid >> 7;            // 0..1
        const float* W = isA ? Wa : Wd;
        const float* wrow = W + c * HID + seg * 64;
        const float* srow = mxs + seg * 64;
        float acc = 0.0f;
        #pragma unroll
        for (int h = 0; h < 64; h += 4) {
            const float4 wv = *reinterpret_cast<const float4*>(wrow + h);
            acc += srow[h] * wv.x + srow[h + 1] * wv.y
                 + srow[h + 2] * wv.z + srow[h + 3] * wv.w;
        }
        sums[tid] = acc;
        __syncthreads();
        if (tid < HID) {
            const float s = sums[c] + sums[c + 128];
            if (isA) Ta[v * HID + c] = s + ba[c];
            else     Td[v * HID + c] = (s + bd[c]) * (1.0f / (float)NPTS);
        }
        __syncthreads();    // drains vmcnt: row stores are at least in L2
        if (tid == 0) {
            __hip_atomic_fetch_add(flag, 1, __ATOMIC_RELEASE,
                                   __HIP_MEMORY_SCOPE_AGENT);
        }
    }
    __syncthreads();        // hist zero visible to all waves

    // ================= per-point pipeline =================
    const int b = blk >> 10;
    const int i = blk & 1023;
    const float* P = pts + (size_t)b * NPTS * 3;
    const float px = P[i * 3 + 0];
    const float py = P[i * 3 + 1];
    const float pz = P[i * 3 + 2];

    // ---- phase 1: 4 distances/lane (raw pts, L1-resident) + per-wave hist ----
    float d4[4];
    int q4[4];
    const int jb = w * 256;
    #pragma unroll
    for (int s = 0; s < 4; ++s) {
        const int j = jb + s * 64 + lane;
        const float dx = px - P[j * 3 + 0];
        const float dy = py - P[j * 3 + 1];
        const float dz = pz - P[j * 3 + 2];
        const float dd = sqrtf(dx * dx + dy * dy + dz * dz);
        d4[s] = dd;
        float qq = rintf(dd / 0.2f);    // matches jnp.round (half-to-even)
        qq = fminf(fmaxf(qq, 0.0f), 255.0f);
        q4[s] = (int)qq;
        atomicAdd(&h4[w][q4[s]], 1);
    }
    __syncthreads();

    // ---- merge hists ----
    const int hsum = h4[0][tid] + h4[1][tid] + h4[2][tid] + h4[3][tid];
    h4[0][tid] = hsum;
    __syncthreads();
    const int* hist = h4[0];

    // ---- scan bins 0..63 for b10; maxbin via ballots (per-wave redundant) ----
    int cum = hist[lane];
    #pragma unroll
    for (int off = 1; off < 64; off <<= 1) {
        const int n_ = __shfl_up(cum, off);
        if (lane >= off) cum += n_;
    }
    const unsigned long long bal = __ballot(cum >= KNN);
    const unsigned long long nz0 = __ballot(hist[lane] != 0);
    const unsigned long long nz1 = __ballot(hist[64 + lane] != 0);
    const unsigned long long nz2 = __ballot(hist[128 + lane] != 0);
    const unsigned long long nz3 = __ballot(hist[192 + lane] != 0);
    int maxbin;
    if (nz3)      maxbin = 192 + 63 - __clzll((long long)nz3);
    else if (nz2) maxbin = 128 + 63 - __clzll((long long)nz2);
    else if (nz1) maxbin = 64 + 63 - __clzll((long long)nz1);
    else          maxbin = 63 - __clzll((long long)nz0);

    int b10 = 0, c = 0;
    if (bal) { b10 = __ffsll(bal) - 1; c = __shfl(cum, b10); }
    const bool fast = (bal != 0ull) && (c <= 64);   // block-uniform

    if (fast) {
        // candidates = all points with bin <= b10 (superset of top-10, c <= 64)
        #pragma unroll
        for (int s = 0; s < 4; ++s) {
            if (q4[s] <= b10) {
                const int pp = atomicAdd(&ccnt, 1);
                cd[pp] = d4[s];
                cidx[pp] = jb + s * 64 + lane;
            }
        }
        __syncthreads();
        if (tid < c) {
            const float md = cd[tid];
            const int mi = cidx[tid];
            int rank = 0;
            #pragma unroll 8
            for (int pp = 0; pp < c; ++pp) {
                const float od = cd[pp];
                const int oi = cidx[pp];
                rank += (od < md || (od == md && oi < mi)) ? 1 : 0;
            }
            if (rank < KNN) nn[rank] = mi;
        }
        __syncthreads();
    } else {
        // fallback: each wave top-10 of its 256 points, then 40-way rank merge
        unsigned valid = 0xfu;
        float keep_d = 0.0f;
        int keep_i = 0;
        for (int r = 0; r < KNN; ++r) {
            float bv = FLT_MAX_;
            int bi = 0x7fffffff;
            #pragma unroll
            for (int s = 0; s < 4; ++s) {
                if (valid & (1u << s)) {
                    const float v_ = d4[s];
                    const int id_ = jb + s * 64 + lane;
                    if (v_ < bv || (v_ == bv && id_ < bi)) { bv = v_; bi = id_; }
                }
            }
            #pragma unroll
            for (int off = 32; off > 0; off >>= 1) {
                const float ov = __shfl_xor(bv, off);
                const int oi = __shfl_xor(bi, off);
                if (ov < bv || (ov == bv && oi < bi)) { bv = ov; bi = oi; }
            }
            const int loc = bi - jb;
            if (loc >= 0 && loc < 256 && lane == (loc & 63)) valid &= ~(1u << (loc >> 6));
            if (lane == r) { keep_d = bv; keep_i = bi; }
        }
        if (lane < KNN) { cd[w * KNN + lane] = keep_d; cidx[w * KNN + lane] = keep_i; }
        __syncthreads();
        if (tid < 4 * KNN) {
            const float md = cd[tid];
            const int mi = cidx[tid];
            int rank = 0;
            for (int pp = 0; pp < 4 * KNN; ++pp) {
                const float od = cd[pp];
                const int oi = cidx[pp];
                rank += (od < md || (od == md && oi < mi)) ? 1 : 0;
            }
            if (rank < KNN) nn[rank] = mi;
        }
        __syncthreads();
    }

    // ---- phases 3+4 fused: each pair recomputes both unit vectors ----
    if (tid < KNN * KNN) {
        const int k = tid / KNN, l = tid % KNN;
        const int jk = nn[k], jl = nn[l];
        const float kx = P[jk * 3 + 0] - px;
        const float ky = P[jk * 3 + 1] - py;
        const float kz = P[jk * 3 + 2] - pz;
        const float dk = sqrtf(kx * kx + ky * ky + kz * kz) + 1e-8f;
        const float lx = P[jl * 3 + 0] - px;
        const float ly = P[jl * 3 + 1] - py;
        const float lz = P[jl * 3 + 2] - pz;
        const float dl = sqrtf(lx * lx + ly * ly + lz * lz) + 1e-8f;
        float cc = (kx / dk) * (lx / dl) + (ky / dk) * (ly / dl) + (kz / dk) * (lz / dl);
        cc = fminf(fmaxf(cc, -1.0f), 1.0f);
        const float ang = acosf(cc);
        float q = rintf(ang * (float)(180.0 / (15.0 * M_PI)));
        q = fminf(fmaxf(q, 0.0f), 15.0f);
        atomicOr(&amask_s, 1u << (int)q);
    }
    __syncthreads();

    // ---- wait for LUT producers (usually already done) ----
    if (tid == 0) {
        while (__hip_atomic_load(flag, __ATOMIC_ACQUIRE,
                                 __HIP_MEMORY_SCOPE_AGENT) < NROWS) {
            __builtin_amdgcn_s_sleep(2);
        }
    }
    __syncthreads();

    // ---- phase 5: split even/odd bins + low/high mask across half-blocks ----
    const unsigned am = amask_s;
    const int c7 = tid & 127;
    const int half = tid >> 7;
    float s = 0.0f;
    const float* tdc = Td + c7;
    #pragma unroll 4
    for (int v = half; v <= maxbin; v += 2) {
        s += (float)hist[v] * tdc[v * HID];   // zero bins add exact 0.0f
    }
    float mx = -FLT_MAX_;
    const float* tac = Ta + c7;
    #pragma unroll
    for (int v = 0; v < 8; ++v) {
        const int vv = half * 8 + v;
        const float tv = tac[vv * HID];
        if (am & (1u << vv)) mx = fmaxf(mx, tv);
    }
    sums[tid] = s;
    mxs[tid] = mx;
    __syncthreads();
    if (tid < HID) {
        out[(size_t)blk * HID + tid] =
            (sums[tid] + sums[tid + 128]) + fmaxf(mxs[tid], mxs[tid + 128]);
    }
}

// ===========================================================================
// Fallback path (proven round-4 kernels), used if nP > 2048.
// ===========================================================================
__global__ __launch_bounds__(512) void gse_build_tables(
    const float* __restrict__ Wd, const float* __restrict__ bd,
    const float* __restrict__ Wa, const float* __restrict__ ba,
    const float* __restrict__ pts, int nP,
    float* __restrict__ Td, float* __restrict__ Ta, float4* __restrict__ P4) {
    const int blk = blockIdx.x;
    const int tid = threadIdx.x;

    if (blk >= 272) {
        const int idx = (blk - 272) * 512 + tid;
        if (idx < nP) {
            P4[idx] = make_float4(pts[idx * 3 + 0], pts[idx * 3 + 1],
                                  pts[idx * 3 + 2], 0.0f);
        }
        return;
    }

    __shared__ float S[HID];
    __shared__ float part[512];
    const bool isA = (blk >= 256);
    const int v = isA ? blk - 256 : blk;
    const int c = tid & 127;
    const int seg = tid >> 7;

    if (tid < HID) {
        const int m = tid >> 1;
        const float dtm = expf((float)m * (float)(-9.210340371976184 / 64.0));
        const float arg = (float)v * dtm;
        S[tid] = (tid & 1) ? cosf(arg) : sinf(arg);
    }
    __syncthreads();

    const float* W = isA ? Wa : Wd;
    const float* wrow = W + c * HID + seg * 32;
    const float* srow = S + seg * 32;
    float acc = 0.0f;
    #pragma unroll
    for (int h = 0; h < 32; h += 4) {
        const float4 wv = *reinterpret_cast<const float4*>(wrow + h);
        acc += srow[h] * wv.x + srow[h + 1] * wv.y + srow[h + 2] * wv.z + srow[h + 3] * wv.w;
    }
    part[tid] = acc;
    __syncthreads();

    if (tid < HID) {
        const float s = (part[c] + part[c + 128]) + (part[c + 256] + part[c + 384]);
        if (isA) Ta[v * HID + c] = s + ba[c];
        else     Td[v * HID + c] = (s + bd[c]) * (1.0f / (float)NPTS);
    }
}

__global__ __launch_bounds__(256, 8) void gse_main(
    const float4* __restrict__ P4,
    const float* __restrict__ Td,
    const float* __restrict__ Ta,
    float* __restrict__ out) {
    const int gid = blockIdx.x;
    const int b = gid >> 10;
    const int i = gid & 1023;
    const float4* P = P4 + (size_t)b * NPTS;
    const int tid = threadIdx.x;
    const int lane = tid & 63;
    const int w = tid >> 6;

    __shared__ int h4[4][256];
    __shared__ float cd[64];
    __shared__ int cidx[64];
    __shared__ int nn[KNN];
    __shared__ float uxs[KNN], uys[KNN], uzs[KNN];
    __shared__ float sums[256], mxs[256];
    __shared__ unsigned amask_s;
    __shared__ int ccnt;

    {
        int* hf = (int*)h4;
        hf[tid] = 0; hf[tid + 256] = 0; hf[tid + 512] = 0; hf[tid + 768] = 0;
    }
    if (tid == 0) { amask_s = 0u; ccnt = 0; }
    const float4 p = P[i];
    __syncthreads();

    float d4[4];
    int q4[4];
    const int jb = w * 256;
    #pragma unroll
    for (int s = 0; s < 4; ++s) {
        const int j = jb + s * 64 + lane;
        const float4 q = P[j];
        const float dx = p.x - q.x;
        const float dy = p.y - q.y;
        const float dz = p.z - q.z;
        const float dd = sqrtf(dx * dx + dy * dy + dz * dz);
        d4[s] = dd;
        float qq = rintf(dd / 0.2f);
        qq = fminf(fmaxf(qq, 0.0f), 255.0f);
        q4[s] = (int)qq;
        atomicAdd(&h4[w][q4[s]], 1);
    }
    __syncthreads();

    const int hsum = h4[0][tid] + h4[1][tid] + h4[2][tid] + h4[3][tid];
    h4[0][tid] = hsum;
    __syncthreads();
    const int* hist = h4[0];

    int cum = hist[lane];
    #pragma unroll
    for (int off = 1; off < 64; off <<= 1) {
        const int n_ = __shfl_up(cum, off);
        if (lane >= off) cum += n_;
    }
    const unsigned long long bal = __ballot(cum >= KNN);
    const unsigned long long nz0 = __ballot(hist[lane] != 0);
    const unsigned long long nz1 = __ballot(hist[64 + lane] != 0);
    const unsigned long long nz2 = __ballot(hist[128 + lane] != 0);
    const unsigned long long nz3 = __ballot(hist[192 + lane] != 0);
    int maxbin;
    if (nz3)      maxbin = 192 + 63 - __clzll((long long)nz3);
    else if (nz2) maxbin = 128 + 63 - __clzll((long long)nz2);
    else if (nz1) maxbin = 64 + 63 - __clzll((long long)nz1);
    else          maxbin = 63 - __clzll((long long)nz0);

    int b10 = 0, c = 0;
    if (bal) { b10 = __ffsll(bal) - 1; c = __shfl(cum, b10); }
    const bool fast = (bal != 0ull) && (c <= 64);

    if (fast) {
        #pragma unroll
        for (int s = 0; s < 4; ++s) {
            if (q4[s] <= b10) {
                const int pp = atomicAdd(&ccnt, 1);
                cd[pp] = d4[s];
                cidx[pp] = jb + s * 64 + lane;
            }
        }
        __syncthreads();
        if (tid < c) {
            const float md = cd[tid];
            const int mi = cidx[tid];
            int rank = 0;
            #pragma unroll 8
            for (int pp = 0; pp < c; ++pp) {
                const float od = cd[pp];
                const int oi = cidx[pp];
                rank += (od < md || (od == md && oi < mi)) ? 1 : 0;
            }
            if (rank < KNN) nn[rank] = mi;
        }
        __syncthreads();
    } else {
        unsigned valid = 0xfu;
        float keep_d = 0.0f;
        int keep_i = 0;
        for (int r = 0; r < KNN; ++r) {
            float bv = FLT_MAX_;
            int bi = 0x7fffffff;
            #pragma unroll
            for (int s = 0; s < 4; ++s) {
                if (valid & (1u << s)) {
                    const float v_ = d4[s];
                    const int id_ = jb + s * 64 + lane;
                    if (v_ < bv || (v_ == bv && id_ < bi)) { bv = v_; bi = id_; }
                }
            }
            #pragma unroll
            for (int off = 32; off > 0; off >>= 1) {
                const float ov = __shfl_xor(bv, off);
                const int oi = __shfl_xor(bi, off);
                if (ov < bv || (ov == bv && oi < bi)) { bv = ov; bi = oi; }
            }
            const int loc = bi - jb;
            if (loc >= 0 && loc < 256 && lane == (loc & 63)) valid &= ~(1u << (loc >> 6));
            if (lane == r) { keep_d = bv; keep_i = bi; }
        }
        if (lane < KNN) { cd[w * KNN + lane] = keep_d; cidx[w * KNN + lane] = keep_i; }
        __syncthreads();
        if (tid < 4 * KNN) {
            const float md = cd[tid];
            const int mi = cidx[tid];
            int rank = 0;
            for (int pp = 0; pp < 4 * KNN; ++pp) {
                const float od = cd[pp];
                const int oi = cidx[pp];
                rank += (od < md || (od == md && oi < mi)) ? 1 : 0;
            }
            if (rank < KNN) nn[rank] = mi;
        }
        __syncthreads();
    }

    if (tid < KNN) {
        const float4 qn = P[nn[tid]];
        const float vx = qn.x - p.x;
        const float vy = qn.y - p.y;
        const float vz = qn.z - p.z;
        const float nrm = sqrtf(vx * vx + vy * vy + vz * vz);
        const float den = nrm + 1e-8f;
        uxs[tid] = vx / den; uys[tid] = vy / den; uzs[tid] = vz / den;
    }
    __syncthreads();

    if (tid < KNN * KNN) {
        const int k = tid / KNN, l = tid % KNN;
        float cc = uxs[k] * uxs[l] + uys[k] * uys[l] + uzs[k] * uzs[l];
        cc = fminf(fmaxf(cc, -1.0f), 1.0f);
        const float ang = acosf(cc);
        float q = rintf(ang * (float)(180.0 / (15.0 * M_PI)));
        q = fminf(fmaxf(q, 0.0f), 15.0f);
        atomicOr(&amask_s, 1u << (int)q);
    }
    __syncthreads();

    const unsigned am = amask_s;
    const int c7 = tid & 127;
    const int half = tid >> 7;
    float s = 0.0f;
    const float* tdc = Td + c7;
    #pragma unroll 4
    for (int v = half; v <= maxbin; v += 2) {
        s += (float)hist[v] * tdc[v * HID];
    }
    float mx = -FLT_MAX_;
    const float* tac = Ta + c7;
    #pragma unroll
    for (int v = 0; v < 8; ++v) {
        const int vv = half * 8 + v;
        const float tv = tac[vv * HID];
        if (am & (1u << vv)) mx = fmaxf(mx, tv);
    }
    sums[tid] = s;
    mxs[tid] = mx;
    __syncthreads();
    if (tid < HID) {
        out[(size_t)gid * HID + tid] =
            (sums[tid] + sums[tid + 128]) + fmaxf(mxs[tid], mxs[tid + 128]);
    }
}

extern "C" void kernel_launch(void* const* d_in, const int* in_sizes, int n_in,
                              void* d_out, int out_size, void* d_ws, size_t ws_size,
                              hipStream_t stream) {
    const float* pts = (const float*)d_in[0];
    const float* Wd  = (const float*)d_in[1];
    const float* bd  = (const float*)d_in[2];
    const float* Wa  = (const float*)d_in[3];
    const float* ba  = (const float*)d_in[4];
    float* out = (float*)d_out;

    const int B = in_sizes[0] / (NPTS * 3);
    const int nP = B * NPTS;

    float* Td = (float*)d_ws;                        // 256*128*4 = 128 KiB
    float* Ta = Td + 256 * HID;                      // 16*128*4  =   8 KiB
    int* flag = (int*)(Ta + 16 * HID);               // 4 B
    float4* P4 = (float4*)((char*)d_ws + 140 * 1024); // fallback scratch

    if (nP <= 2048 && nP >= NROWS) {
        hipMemsetAsync(flag, 0, sizeof(int), stream);
        gse_one<<<nP, 256, 0, stream>>>(pts, Wd, bd, Wa, ba, Td, Ta, flag, out);
    } else {
        const int nconv = (nP + 511) / 512;
        gse_build_tables<<<272 + nconv, 512, 0, stream>>>(Wd, bd, Wa, ba, pts, nP, Td, Ta, P4);
        gse_main<<<nP, 256, 0, stream>>>(P4, Td, Ta, out);
    }
}